// Round 10
// baseline (380.088 us; speedup 1.0000x reference)
//
#include <hip/hip_runtime.h>

typedef __attribute__((ext_vector_type(8))) short short8v;
typedef __attribute__((ext_vector_type(4))) float f32x4;

// ws layout (float offsets)
//  [0 .. 163839]   bf16 panel [gate(160)][k(2048)]  (ushort)
#define WSL   163840           // loss column (80)
#define WSC1  (WSL+80)         // folded gate-1 constants (80)
#define WSC2  (WSC1+80)        // folded gate-2 constants (80)
#define WSPF  (WSC2+80)        // poly factor

__device__ __forceinline__ float fsig(float x){ return 1.0f/(1.0f + __expf(-x)); }
__device__ __forceinline__ float ftanh(float x){ float e = __expf(2.0f*x); return 1.0f - 2.0f/(e+1.0f); }
__device__ __forceinline__ unsigned short f2bf_rne(float f){
  unsigned u = __float_as_uint(f);
  u += 0x7fffu + ((u >> 16) & 1u);
  return (unsigned short)(u >> 16);
}
__device__ __forceinline__ unsigned pack2bf(float lo, float hi){
  unsigned a = __float_as_uint(lo) + 0x8000u;
  unsigned b = __float_as_uint(hi) + 0x8000u;
  return (a >> 16) | (b & 0xFFFF0000u);
}

// prep: 160 blocks repack W_ih1 -> bf16 panel + fold constants.
__global__ __launch_bounds__(256,1) void prep_kernel(
    const float* __restrict__ W_ih1, const float* __restrict__ b_ih1,
    const float* __restrict__ W_hh1, const float* __restrict__ b_hh1,
    const float* __restrict__ b_ih2, const float* __restrict__ W_hh2,
    const float* __restrict__ b_hh2, const float* __restrict__ h1_0,
    const float* __restrict__ h2_0, const float* __restrict__ alpha_raw,
    const int* __restrict__ t, float* __restrict__ ws)
{
  const int g = blockIdx.x;            // 160 gates: 0..79 x-part, 80..159 grad-part
  const int wr = (g < 80) ? g : g - 80;
  const float* src = W_ih1 + (size_t)wr*4097 + ((g < 80) ? 0 : 2049);
  unsigned short* dst = (unsigned short*)ws + (size_t)g*2048;
  for (int k = threadIdx.x; k < 2048; k += 256) dst[k] = f2bf_rne(src[k]);
  if (g == 0) {
    const int tix = threadIdx.x;
    if (tix < 80) {
      float s = b_ih1[tix] + b_hh1[tix];
      for (int j = 0; j < 20; ++j) s += W_hh1[tix*20+j]*h1_0[j];
      ws[WSC1+tix] = s;
    } else if (tix < 160) {
      const int kk = tix - 80;
      float s = b_ih2[kk] + b_hh2[kk];
      for (int j = 0; j < 20; ++j) s += W_hh2[kk*20+j]*h2_0[j];
      ws[WSC2+kk] = s;
    } else if (tix < 240) {
      const int kk = tix - 160;
      ws[WSL+kk] = W_ih1[(size_t)kk*4097 + 2048];   // loss column
    } else if (tix == 240) {
      const float tv = (float)(*t);
      float pf = 0.f, term = 1.f;
      for (int j = 0; j < 3; ++j) {
        float a = alpha_raw[j];
        float sp = (a > 20.f) ? a : log1pf(__expf(a));
        pf += sp*term; term *= tv;                   // t^0 == 1 even at t=0
      }
      pf *= powf(0.99f, tv);
      ws[WSPF] = pf;
    }
  }
}

// Mega: 256 blocks x 1024 thr (16 waves = 2 parts x 8 K-slices). Block = 16 rows,
// full K. Per 256-k chunk: stage 160x256 bf16 panel slice (80KB, XOR-swizzled)
// into LDS from L2, each wave does 1 MFMA k-step x 5 gate-tiles. Partials and
// row norms combine in LDS (pbuf aliases the dead stage buffer); gates->cells->
// output GEMV all in-block. No global intermediates.
__global__ __launch_bounds__(1024,1) void mega_kernel(
    const float* __restrict__ x, const float* __restrict__ loss,
    const float* __restrict__ grad, const float* __restrict__ W_ih2,
    const float* __restrict__ W_out, const float* __restrict__ b_out,
    const float* __restrict__ c1_0, const float* __restrict__ c2_0,
    const float* ws, float* __restrict__ out)
{
  __shared__ float smem[20480];        // 80 KB: stage [160][512B] / pbuf alias
  __shared__ float wih2s[1600];
  __shared__ float g1[16][80];
  __shared__ float h1s[16][20], h2s[16][20];
  __shared__ float c10[20], c20[20];
  __shared__ float invX[16], invG[16], lscA[16], axp[16];
  __shared__ unsigned smax[2][16];

  const int tid  = threadIdx.x;
  const int w    = tid >> 6, lane = tid & 63;
  const int part = w & 1, ksw = w >> 1;          // part 0=x 1=grad; ksw 0..7
  const int m    = lane & 15, kg = lane >> 4;
  const int r0   = blockIdx.x * 16;

  unsigned short* bs = (unsigned short*)smem;
  const unsigned short* panel = (const unsigned short*)ws;

  for (int i = tid; i < 1600; i += 1024) wih2s[i] = W_ih2[i];
  if (tid < 20) { c10[tid] = c1_0[tid]; c20[tid] = c2_0[tid]; }
  if (tid < 32) smax[tid >> 4][tid & 15] = 0u;

  const float* Ap = (part ? grad : x) + (size_t)(r0 + m)*2048 + ksw*32 + kg*8;
  const int xk  = (m & 7) << 4;
  const int kof = (ksw*64 + kg*16) ^ xk;

  f32x4 acc[5];
  #pragma unroll
  for (int t = 0; t < 5; ++t) acc[t] = (f32x4){0.f,0.f,0.f,0.f};
  float vm = 0.f;

  f32x4 a0 = __builtin_nontemporal_load((const f32x4*)Ap);
  f32x4 a1 = __builtin_nontemporal_load((const f32x4*)(Ap + 4));

  #pragma unroll 1
  for (int c = 0; c < 8; ++c) {
    // ---- stage chunk c: 160 gates x 32 chunks of 16B each (80 KB) ----
    #pragma unroll
    for (int q = 0; q < 5; ++q) {
      const int j = q*1024 + tid;      // 0..5119
      const int g = j >> 5, ku = j & 31;
      const uint4 v = *(const uint4*)(panel + (size_t)g*2048 + c*256 + ku*8);
      *(uint4*)((char*)bs + g*512 + ((ku*16) ^ ((g & 7) << 4))) = v;
    }
    __syncthreads();
    // prefetch next chunk's A
    const float* pn = Ap + ((c < 7) ? (c + 1)*256 : 0);
    const f32x4 n0 = __builtin_nontemporal_load((const f32x4*)pn);
    const f32x4 n1 = __builtin_nontemporal_load((const f32x4*)(pn + 4));
    // ---- one k-step: 5 MFMAs over this part's 80 gates ----
    vm = fmaxf(vm, fmaxf(fmaxf(fabsf(a0.x),fabsf(a0.y)), fmaxf(fabsf(a0.z),fabsf(a0.w))));
    vm = fmaxf(vm, fmaxf(fmaxf(fabsf(a1.x),fabsf(a1.y)), fmaxf(fabsf(a1.z),fabsf(a1.w))));
    union { unsigned u[4]; short8v v; } A_;
    A_.u[0] = pack2bf(a0.x, a0.y);
    A_.u[1] = pack2bf(a0.z, a0.w);
    A_.u[2] = pack2bf(a1.x, a1.y);
    A_.u[3] = pack2bf(a1.z, a1.w);
    const short8v af = A_.v;
    #pragma unroll
    for (int t = 0; t < 5; ++t) {
      const int lg = part*80 + t*16 + m;
      const short8v bf = *(const short8v*)((char*)bs + lg*512 + kof);
      acc[t] = __builtin_amdgcn_mfma_f32_16x16x32_bf16(af, bf, acc[t], 0, 0, 0);
    }
    __syncthreads();                   // all reads done before next stage
    a0 = n0; a1 = n1;
  }

  // ---- row inf-norm: reduce kg lanes, then LDS atomicMax across ksw waves ----
  vm = fmaxf(vm, __shfl_xor(vm, 16));
  vm = fmaxf(vm, __shfl_xor(vm, 32));
  if (lane < 16) atomicMax(&smax[part][m], __float_as_uint(vm));

  // ---- combine wave partials in LDS (pbuf aliases dead stage buffer) ----
  float* pbuf = smem;                  // [2][16][168]
  for (int i = tid; i < 2*16*168; i += 1024) pbuf[i] = 0.f;
  __syncthreads();
  #pragma unroll
  for (int t = 0; t < 5; ++t)
    #pragma unroll
    for (int r = 0; r < 4; ++r)
      atomicAdd(&pbuf[part*2688 + (kg*4 + r)*168 + t*16 + m], acc[t][r]);
  __syncthreads();

  if (tid < 16) {
    float ax = __uint_as_float(smax[0][tid]); ax = (ax > 0.f) ? ax : 1.0f;
    invX[tid] = 1.0f/ax;
    axp[tid]  = ws[WSPF] * ax;
    float ag = __uint_as_float(smax[1][tid]); ag = (ag > 0.f) ? ag : 1.0f;
    invG[tid] = 1.0f/ag;
    float l  = loss[r0 + tid];
    float al = fabsf(l); al = (al > 0.f) ? al : 1.0f;
    lscA[tid] = l / al;
  }
  __syncthreads();

  for (int idx = tid; idx < 1280; idx += 1024) {     // gates 1 (16x80)
    const int r = idx / 80, k2 = idx - r*80;
    g1[r][k2] = pbuf[r*168 + k2]*invX[r] + pbuf[2688 + r*168 + k2]*invG[r]
              + ws[WSL+k2]*lscA[r] + ws[WSC1+k2];
  }
  __syncthreads();

  if (tid < 320) {                                   // cell 1
    const int r = tid / 20, j = tid - r*20;
    const float gi = g1[r][j], gf = g1[r][20+j], gc = g1[r][40+j], go = g1[r][60+j];
    const float c1 = fsig(gf)*c10[j] + fsig(gi)*ftanh(gc);
    h1s[r][j] = fsig(go)*ftanh(c1);
  }
  __syncthreads();

  for (int idx = tid; idx < 1280; idx += 1024) {     // gates 2
    const int r = idx / 80, k2 = idx - r*80;
    float s = ws[WSC2+k2];
    #pragma unroll
    for (int j = 0; j < 20; ++j) s += wih2s[k2*20+j]*h1s[r][j];
    g1[r][k2] = s;
  }
  __syncthreads();

  if (tid < 320) {                                   // cell 2
    const int r = tid / 20, j = tid - r*20;
    const float gi = g1[r][j], gf = g1[r][20+j], gc = g1[r][40+j], go = g1[r][60+j];
    const float c2v = fsig(gf)*c20[j] + fsig(gi)*ftanh(gc);
    h2s[r][j] = fsig(go)*ftanh(c2v);
  }
  __syncthreads();

  // ---- output GEMV: 2 d-cols per thread x 16 rows, W_out from L2 ----
  #pragma unroll
  for (int q = 0; q < 2; ++q) {
    const int d = q*1024 + tid;
    const float4* wr = (const float4*)(W_out + (size_t)d*20);
    const float4 w0 = wr[0], w1 = wr[1], w2 = wr[2], w3 = wr[3], w4 = wr[4];
    const float bo = b_out[d];
    #pragma unroll
    for (int r = 0; r < 16; ++r) {
      const float4* hp = (const float4*)&h2s[r][0];
      const float4 h0 = hp[0], h1v = hp[1], h2v = hp[2], h3v = hp[3], h4v = hp[4];
      float v = bo;
      v += w0.x*h0.x  + w0.y*h0.y  + w0.z*h0.z  + w0.w*h0.w;
      v += w1.x*h1v.x + w1.y*h1v.y + w1.z*h1v.z + w1.w*h1v.w;
      v += w2.x*h2v.x + w2.y*h2v.y + w2.z*h2v.z + w2.w*h2v.w;
      v += w3.x*h3v.x + w3.y*h3v.y + w3.z*h3v.z + w3.w*h3v.w;
      v += w4.x*h4v.x + w4.y*h4v.y + w4.z*h4v.z + w4.w*h4v.w;
      __builtin_nontemporal_store(axp[r] * ftanh(v),
                                  &out[(size_t)(r0+r)*2048 + d]);
    }
  }
}

extern "C" void kernel_launch(void* const* d_in, const int* in_sizes, int n_in,
                              void* d_out, int out_size, void* d_ws, size_t ws_size,
                              hipStream_t stream)
{
  const float* x      = (const float*)d_in[0];
  const float* loss   = (const float*)d_in[1];
  const float* grad   = (const float*)d_in[2];
  const float* W_ih1  = (const float*)d_in[3];
  const float* b_ih1  = (const float*)d_in[4];
  const float* W_hh1  = (const float*)d_in[5];
  const float* b_hh1  = (const float*)d_in[6];
  const float* W_ih2  = (const float*)d_in[7];
  const float* b_ih2  = (const float*)d_in[8];
  const float* W_hh2  = (const float*)d_in[9];
  const float* b_hh2  = (const float*)d_in[10];
  const float* W_out  = (const float*)d_in[11];
  const float* b_out  = (const float*)d_in[12];
  const float* h1_0   = (const float*)d_in[13];
  const float* c1_0   = (const float*)d_in[14];
  const float* h2_0   = (const float*)d_in[15];
  const float* c2_0   = (const float*)d_in[16];
  const float* alpha  = (const float*)d_in[17];
  const int*   t      = (const int*)d_in[18];
  float* ws  = (float*)d_ws;
  float* out = (float*)d_out;

  hipLaunchKernelGGL(prep_kernel, dim3(160), dim3(256), 0, stream,
                     W_ih1, b_ih1, W_hh1, b_hh1, b_ih2, W_hh2, b_hh2,
                     h1_0, h2_0, alpha, t, ws);
  hipLaunchKernelGGL(mega_kernel, dim3(256), dim3(1024), 0, stream,
                     x, loss, grad, W_ih2, W_out, b_out, c1_0, c2_0, ws, out);
}

// Round 11
// 355.022 us; speedup vs baseline: 1.0706x; 1.0706x over previous
//
#include <hip/hip_runtime.h>

typedef __attribute__((ext_vector_type(8))) short short8v;
typedef __attribute__((ext_vector_type(4))) float f32x4;

// ws layout (float offsets)
//  [0 .. 163839]   bf16 panel [gate(160)][k(2048)]  (ushort)
#define WSL   163840           // loss column (80)
#define WSC1  (WSL+80)         // folded gate-1 constants (80)
#define WSC2  (WSC1+80)        // folded gate-2 constants (80)
#define WSPF  (WSC2+80)        // poly factor

__device__ __forceinline__ float fsig(float x){ return 1.0f/(1.0f + __expf(-x)); }
__device__ __forceinline__ float ftanh(float x){ float e = __expf(2.0f*x); return 1.0f - 2.0f/(e+1.0f); }
__device__ __forceinline__ unsigned short f2bf_rne(float f){
  unsigned u = __float_as_uint(f);
  u += 0x7fffu + ((u >> 16) & 1u);
  return (unsigned short)(u >> 16);
}
__device__ __forceinline__ unsigned pack2bf(float lo, float hi){
  unsigned a = __float_as_uint(lo) + 0x8000u;
  unsigned b = __float_as_uint(hi) + 0x8000u;
  return (a >> 16) | (b & 0xFFFF0000u);
}

// prep: 320 blocks, b = gate*2 + half-krange; block 0 also folds constants.
__global__ __launch_bounds__(256,1) void prep_kernel(
    const float* __restrict__ W_ih1, const float* __restrict__ b_ih1,
    const float* __restrict__ W_hh1, const float* __restrict__ b_hh1,
    const float* __restrict__ b_ih2, const float* __restrict__ W_hh2,
    const float* __restrict__ b_hh2, const float* __restrict__ h1_0,
    const float* __restrict__ h2_0, const float* __restrict__ alpha_raw,
    const int* __restrict__ t, float* __restrict__ ws)
{
  const int b = blockIdx.x;
  const int g = b >> 1, half = b & 1;        // gate 0..159
  const int wr = (g < 80) ? g : g - 80;
  const float* src = W_ih1 + (size_t)wr*4097 + ((g < 80) ? 0 : 2049) + half*1024;
  unsigned short* dst = (unsigned short*)ws + (size_t)g*2048 + half*1024;
  for (int k = threadIdx.x; k < 1024; k += 256) dst[k] = f2bf_rne(src[k]);
  if (b == 0) {
    const int tix = threadIdx.x;
    if (tix < 80) {
      float s = b_ih1[tix] + b_hh1[tix];
      for (int j = 0; j < 20; ++j) s += W_hh1[tix*20+j]*h1_0[j];
      ws[WSC1+tix] = s;
    } else if (tix < 160) {
      const int kk = tix - 80;
      float s = b_ih2[kk] + b_hh2[kk];
      for (int j = 0; j < 20; ++j) s += W_hh2[kk*20+j]*h2_0[j];
      ws[WSC2+kk] = s;
    } else if (tix < 240) {
      const int kk = tix - 160;
      ws[WSL+kk] = W_ih1[(size_t)kk*4097 + 2048];   // loss column
    } else if (tix == 240) {
      const float tv = (float)(*t);
      float pf = 0.f, term = 1.f;
      for (int j = 0; j < 3; ++j) {
        float a = alpha_raw[j];
        float sp = (a > 20.f) ? a : log1pf(__expf(a));
        pf += sp*term; term *= tv;                   // t^0 == 1 even at t=0
      }
      pf *= powf(0.99f, tv);
      ws[WSPF] = pf;
    }
  }
}

// Fused: 256 blocks x 512 thr (8 waves = 2 parts x 4 K-slices). Block = 16 rows,
// full K. Chunk = 128 cols, single 40KB LDS buffer, T14 split: next chunk's B
// loaded to regs before compute, ds_write after barrier. Everything downstream
// (partials, norms, gates, cells, output GEMV) block-local. No global temps.
__global__ __launch_bounds__(512,1) void fused_kernel(
    const float* __restrict__ x, const float* __restrict__ loss,
    const float* __restrict__ grad, const float* __restrict__ W_ih2,
    const float* __restrict__ W_out, const float* __restrict__ b_out,
    const float* __restrict__ c1_0, const float* __restrict__ c2_0,
    const float* ws, float* __restrict__ out)
{
  __shared__ float smem[10240];        // 40 KB: B-stage [160][256B] / pbuf alias
  __shared__ float wih2s[1600];
  __shared__ float g1[16][80];
  __shared__ float h1s[16][20], h2s[16][20];
  __shared__ float c10[20], c20[20];
  __shared__ float invX[16], invG[16], lscA[16], axp[16];
  __shared__ unsigned smax[2][16];

  const int tid  = threadIdx.x;
  const int w    = tid >> 6, lane = tid & 63;
  const int part = w & 1, ksw = w >> 1;          // part 0=x 1=grad; ksw 0..3
  const int m    = lane & 15, kg = lane >> 4;
  const int r0   = blockIdx.x * 16;

  unsigned short* bs = (unsigned short*)smem;
  const unsigned short* panel = (const unsigned short*)ws;

  for (int i = tid; i < 1600; i += 512) wih2s[i] = W_ih2[i];
  if (tid < 20) { c10[tid] = c1_0[tid]; c20[tid] = c2_0[tid]; }
  if (tid < 32) smax[tid >> 4][tid & 15] = 0u;

  const float* Ap = (part ? grad : x) + (size_t)(r0 + m)*2048 + ksw*32 + kg*8;
  const int xk  = (m & 7) << 4;
  const int kof = (ksw*64 + kg*16) ^ xk;         // read offset within gate row

  // stage mapping: per q (0..4): gate g = q*32 + tg, slot ku; swizzle const/thread
  const int tg = tid >> 4, ku = tid & 15;
  const unsigned short* psrc = panel + (size_t)tg*2048 + ku*8;
  char* pdst = (char*)bs + tg*256 + ((ku*16) ^ ((tg & 7) << 4));

  uint4 st[5];
  f32x4 acc[5];
  #pragma unroll
  for (int t = 0; t < 5; ++t) acc[t] = (f32x4){0.f,0.f,0.f,0.f};
  float vm = 0.f;

  // prologue: stage chunk 0, preload chunk 1 to regs, prefetch A chunk 0
  #pragma unroll
  for (int q = 0; q < 5; ++q)
    st[q] = *(const uint4*)(psrc + (size_t)q*65536);
  f32x4 a0 = __builtin_nontemporal_load((const f32x4*)Ap);
  f32x4 a1 = __builtin_nontemporal_load((const f32x4*)(Ap + 4));
  #pragma unroll
  for (int q = 0; q < 5; ++q)
    *(uint4*)(pdst + q*8192) = st[q];
  #pragma unroll
  for (int q = 0; q < 5; ++q)
    st[q] = *(const uint4*)(psrc + (size_t)q*65536 + 128);
  __syncthreads();

  #pragma unroll 1
  for (int c = 0; c < 16; ++c) {
    // prefetch next chunk's A
    const float* pn = Ap + ((c < 15) ? (c + 1)*128 : 0);
    const f32x4 n0 = __builtin_nontemporal_load((const f32x4*)pn);
    const f32x4 n1 = __builtin_nontemporal_load((const f32x4*)(pn + 4));
    // compute chunk c
    vm = fmaxf(vm, fmaxf(fmaxf(fabsf(a0.x),fabsf(a0.y)), fmaxf(fabsf(a0.z),fabsf(a0.w))));
    vm = fmaxf(vm, fmaxf(fmaxf(fabsf(a1.x),fabsf(a1.y)), fmaxf(fabsf(a1.z),fabsf(a1.w))));
    union { unsigned u[4]; short8v v; } A_;
    A_.u[0] = pack2bf(a0.x, a0.y);
    A_.u[1] = pack2bf(a0.z, a0.w);
    A_.u[2] = pack2bf(a1.x, a1.y);
    A_.u[3] = pack2bf(a1.z, a1.w);
    const short8v af = A_.v;
    #pragma unroll
    for (int t = 0; t < 5; ++t) {
      const int lg = part*80 + t*16 + m;
      const short8v bf = *(const short8v*)((char*)bs + lg*256 + kof);
      acc[t] = __builtin_amdgcn_mfma_f32_16x16x32_bf16(af, bf, acc[t], 0, 0, 0);
    }
    __syncthreads();                   // all reads of bs done
    if (c < 15) {
      #pragma unroll
      for (int q = 0; q < 5; ++q)      // write chunk c+1 (already in regs)
        *(uint4*)(pdst + q*8192) = st[q];
      if (c < 14) {
        #pragma unroll
        for (int q = 0; q < 5; ++q)    // load chunk c+2
          st[q] = *(const uint4*)(psrc + (size_t)q*65536 + (c + 2)*128);
      }
      __syncthreads();                 // bs ready for next compute
    }
    a0 = n0; a1 = n1;
  }

  // ---- row inf-norm: shfl over kg, LDS atomicMax across ksw waves ----
  vm = fmaxf(vm, __shfl_xor(vm, 16));
  vm = fmaxf(vm, __shfl_xor(vm, 32));
  if (lane < 16) atomicMax(&smax[part][m], __float_as_uint(vm));

  // ---- combine wave partials in LDS (pbuf aliases stage buffer) ----
  float* pbuf = smem;                  // [2][16][168]
  for (int i = tid; i < 2*16*168; i += 512) pbuf[i] = 0.f;
  __syncthreads();
  #pragma unroll
  for (int t = 0; t < 5; ++t)
    #pragma unroll
    for (int r = 0; r < 4; ++r)
      atomicAdd(&pbuf[part*2688 + (kg*4 + r)*168 + t*16 + m], acc[t][r]);
  __syncthreads();

  if (tid < 16) {
    float ax = __uint_as_float(smax[0][tid]); ax = (ax > 0.f) ? ax : 1.0f;
    invX[tid] = 1.0f/ax;
    axp[tid]  = ws[WSPF] * ax;
    float ag = __uint_as_float(smax[1][tid]); ag = (ag > 0.f) ? ag : 1.0f;
    invG[tid] = 1.0f/ag;
    float l  = loss[r0 + tid];
    float al = fabsf(l); al = (al > 0.f) ? al : 1.0f;
    lscA[tid] = l / al;
  }
  __syncthreads();

  for (int idx = tid; idx < 1280; idx += 512) {      // gates 1 (16x80)
    const int r = idx / 80, k2 = idx - r*80;
    g1[r][k2] = pbuf[r*168 + k2]*invX[r] + pbuf[2688 + r*168 + k2]*invG[r]
              + ws[WSL+k2]*lscA[r] + ws[WSC1+k2];
  }
  __syncthreads();

  if (tid < 320) {                                   // cell 1
    const int r = tid / 20, j = tid - r*20;
    const float gi = g1[r][j], gf = g1[r][20+j], gc = g1[r][40+j], go = g1[r][60+j];
    const float c1 = fsig(gf)*c10[j] + fsig(gi)*ftanh(gc);
    h1s[r][j] = fsig(go)*ftanh(c1);
  }
  __syncthreads();

  for (int idx = tid; idx < 1280; idx += 512) {      // gates 2
    const int r = idx / 80, k2 = idx - r*80;
    float s = ws[WSC2+k2];
    #pragma unroll
    for (int j = 0; j < 20; ++j) s += wih2s[k2*20+j]*h1s[r][j];
    g1[r][k2] = s;
  }
  __syncthreads();

  if (tid < 320) {                                   // cell 2
    const int r = tid / 20, j = tid - r*20;
    const float gi = g1[r][j], gf = g1[r][20+j], gc = g1[r][40+j], go = g1[r][60+j];
    const float c2v = fsig(gf)*c20[j] + fsig(gi)*ftanh(gc);
    h2s[r][j] = fsig(go)*ftanh(c2v);
  }
  __syncthreads();

  // ---- output GEMV: 4 d-cols per thread x 16 rows, W_out from L2 ----
  #pragma unroll
  for (int q = 0; q < 4; ++q) {
    const int d = q*512 + tid;
    const float4* wr = (const float4*)(W_out + (size_t)d*20);
    const float4 w0 = wr[0], w1 = wr[1], w2 = wr[2], w3 = wr[3], w4 = wr[4];
    const float bo = b_out[d];
    #pragma unroll
    for (int r = 0; r < 16; ++r) {
      const float4* hp = (const float4*)&h2s[r][0];
      const float4 h0 = hp[0], h1v = hp[1], h2v = hp[2], h3v = hp[3], h4v = hp[4];
      float v = bo;
      v += w0.x*h0.x  + w0.y*h0.y  + w0.z*h0.z  + w0.w*h0.w;
      v += w1.x*h1v.x + w1.y*h1v.y + w1.z*h1v.z + w1.w*h1v.w;
      v += w2.x*h2v.x + w2.y*h2v.y + w2.z*h2v.z + w2.w*h2v.w;
      v += w3.x*h3v.x + w3.y*h3v.y + w3.z*h3v.z + w3.w*h3v.w;
      v += w4.x*h4v.x + w4.y*h4v.y + w4.z*h4v.z + w4.w*h4v.w;
      __builtin_nontemporal_store(axp[r] * ftanh(v),
                                  &out[(size_t)(r0+r)*2048 + d]);
    }
  }
}

extern "C" void kernel_launch(void* const* d_in, const int* in_sizes, int n_in,
                              void* d_out, int out_size, void* d_ws, size_t ws_size,
                              hipStream_t stream)
{
  const float* x      = (const float*)d_in[0];
  const float* loss   = (const float*)d_in[1];
  const float* grad   = (const float*)d_in[2];
  const float* W_ih1  = (const float*)d_in[3];
  const float* b_ih1  = (const float*)d_in[4];
  const float* W_hh1  = (const float*)d_in[5];
  const float* b_hh1  = (const float*)d_in[6];
  const float* W_ih2  = (const float*)d_in[7];
  const float* b_ih2  = (const float*)d_in[8];
  const float* W_hh2  = (const float*)d_in[9];
  const float* b_hh2  = (const float*)d_in[10];
  const float* W_out  = (const float*)d_in[11];
  const float* b_out  = (const float*)d_in[12];
  const float* h1_0   = (const float*)d_in[13];
  const float* c1_0   = (const float*)d_in[14];
  const float* h2_0   = (const float*)d_in[15];
  const float* c2_0   = (const float*)d_in[16];
  const float* alpha  = (const float*)d_in[17];
  const int*   t      = (const int*)d_in[18];
  float* ws  = (float*)d_ws;
  float* out = (float*)d_out;

  hipLaunchKernelGGL(prep_kernel, dim3(320), dim3(256), 0, stream,
                     W_ih1, b_ih1, W_hh1, b_hh1, b_ih2, W_hh2, b_hh2,
                     h1_0, h2_0, alpha, t, ws);
  hipLaunchKernelGGL(fused_kernel, dim3(256), dim3(512), 0, stream,
                     x, loss, grad, W_ih2, W_out, b_out, c1_0, c2_0, ws, out);
}

// Round 12
// 63.578 us; speedup vs baseline: 5.9783x; 5.5840x over previous
//
#include <hip/hip_runtime.h>

typedef __attribute__((ext_vector_type(8))) short short8v;
typedef __attribute__((ext_vector_type(4))) float f32x4;

// ws float offsets
#define NORM  0               // [2][16][4096] per-slice row inf-norm maxes
#define H2S   131072          // [4096][20] h2 state
#define AXPF  212992          // [4096] pf * ax[row]
#define PART  217088          // [NS][4096][160] f32 gate partials

__device__ __forceinline__ float fsig(float x){ return 1.0f/(1.0f + __expf(-x)); }
__device__ __forceinline__ float ftanh(float x){ float e = __expf(2.0f*x); return 1.0f - 2.0f/(e+1.0f); }
__device__ __forceinline__ unsigned pack2bf(float lo, float hi){
  unsigned a = __float_as_uint(lo) + 0x8000u;
  unsigned b = __float_as_uint(hi) + 0x8000u;
  return (a >> 16) | (b & 0xFFFF0000u);
}

// GEMM: grid = 64 rowblocks x NS kslices, 512 thr = 8 waves (4 m-tiles x 2 parts).
// Block stages its B slice (160 gates x KS k) DIRECTLY from W_ih1 (f32->bf16,
// XOR-swizzled LDS); per-XCD slice is L2-hot. All 8 A fragments issued upfront
// so HBM latency hides under the stage phase. Per-slice norms, no atomics.
template<int NS>
__global__ __launch_bounds__(512,2) void gemm_kernel(
    const float* __restrict__ x, const float* __restrict__ grad,
    const float* __restrict__ W_ih1, float* __restrict__ ws)
{
  constexpr int KS = 2048 / NS;            // 128 for NS=16
  constexpr int PAIRS = 160 * (KS/2);
  __shared__ unsigned short bs[160*KS];    // 40 KB (NS=16)

  const int tid = threadIdx.x;
  const int w = tid >> 6, lane = tid & 63;
  const int mt = w >> 1, gh = w & 1;       // m-tile 0..3, part 0=x 1=grad
  const int m = lane & 15, kg = lane >> 4;
  const int rb = blockIdx.x / NS, ksl = blockIdx.x % NS;
  const int r0 = rb*64;
  const int kb = ksl*KS;

  // ---- A fragments upfront: 8x16B NT loads in flight during staging ----
  const float* Ap = (gh ? grad : x) + (size_t)(r0 + mt*16 + m)*2048 + kb + kg*8;
  f32x4 a[4][2];
  #pragma unroll
  for (int ks = 0; ks < 4; ++ks) {
    a[ks][0] = __builtin_nontemporal_load((const f32x4*)(Ap + ks*32));
    a[ks][1] = __builtin_nontemporal_load((const f32x4*)(Ap + ks*32 + 4));
  }

  // ---- stage B slice from W_ih1: f32 -> bf16, swizzled ----
  #pragma unroll
  for (int q = 0; q < PAIRS/512; ++q) {
    const int j = q*512 + tid;             // pair index
    const int g = j / (KS/2), p = j % (KS/2);
    const float* src = W_ih1 + (size_t)((g < 80) ? g : g - 80)*4097
                     + ((g < 80) ? 0 : 2049) + kb + 2*p;
    const unsigned pk = pack2bf(src[0], src[1]);
    *(unsigned*)((char*)bs + g*(KS*2)
                 + (((p >> 2)*16) ^ ((g & 7) << 4)) + (p & 3)*4) = pk;
  }
  __syncthreads();

  // ---- 4 k-steps x 5 MFMA ----
  f32x4 acc[5];
  #pragma unroll
  for (int t = 0; t < 5; ++t) acc[t] = (f32x4){0.f,0.f,0.f,0.f};
  float vm = 0.f;
  const int xk = (m & 7) << 4;

  #pragma unroll
  for (int ks = 0; ks < 4; ++ks) {
    const f32x4 a0 = a[ks][0], a1 = a[ks][1];
    vm = fmaxf(vm, fmaxf(fmaxf(fabsf(a0.x),fabsf(a0.y)), fmaxf(fabsf(a0.z),fabsf(a0.w))));
    vm = fmaxf(vm, fmaxf(fmaxf(fabsf(a1.x),fabsf(a1.y)), fmaxf(fabsf(a1.z),fabsf(a1.w))));
    union { unsigned u[4]; short8v v; } A_;
    A_.u[0] = pack2bf(a0.x, a0.y);
    A_.u[1] = pack2bf(a0.z, a0.w);
    A_.u[2] = pack2bf(a1.x, a1.y);
    A_.u[3] = pack2bf(a1.z, a1.w);
    const short8v af = A_.v;
    const int kof = (ks*64 + kg*16) ^ xk;
    #pragma unroll
    for (int t = 0; t < 5; ++t) {
      const int lg = gh*80 + t*16 + m;
      const short8v bf = *(const short8v*)((char*)bs + lg*(KS*2) + kof);
      acc[t] = __builtin_amdgcn_mfma_f32_16x16x32_bf16(af, bf, acc[t], 0, 0, 0);
    }
  }

  // ---- per-slice row inf-norm: reduce kg lanes, exclusive store ----
  vm = fmaxf(vm, __shfl_xor(vm, 16));
  vm = fmaxf(vm, __shfl_xor(vm, 32));
  if (lane < 16)
    ws[NORM + ((size_t)gh*NS + ksl)*4096 + r0 + mt*16 + m] = vm;

  // ---- per-slice partials (exclusive ownership), NT stores ----
  float* pp = ws + PART + ((size_t)ksl*4096 + r0 + mt*16 + kg*4)*160 + gh*80 + m;
  #pragma unroll
  for (int t = 0; t < 5; ++t)
    #pragma unroll
    for (int r = 0; r < 4; ++r)
      __builtin_nontemporal_store(acc[t][r], pp + (size_t)r*160 + t*16);
}

// tail: 512 blocks x 256 thr; 8 rows. Computes folded constants locally,
// reduces NS slices + norms, gates -> cells -> h2 + pf*ax to ws.
template<int NS>
__global__ __launch_bounds__(256,4) void tail_kernel(
    const float* __restrict__ loss, const float* __restrict__ W_ih1,
    const float* __restrict__ b_ih1, const float* __restrict__ W_hh1,
    const float* __restrict__ b_hh1, const float* __restrict__ W_ih2,
    const float* __restrict__ b_ih2, const float* __restrict__ W_hh2,
    const float* __restrict__ b_hh2, const float* __restrict__ h1_0,
    const float* __restrict__ h2_0, const float* __restrict__ c1_0,
    const float* __restrict__ c2_0, const float* __restrict__ alpha_raw,
    const int* __restrict__ tptr, const float* ws, float* __restrict__ wsw)
{
  __shared__ float raw[8][160];
  __shared__ float g1[8][80];
  __shared__ float wih2s[1600];
  __shared__ float h1s[8][20];
  __shared__ float c1c[80], c2c[80], lcol[80];
  __shared__ float c10[20], c20[20];
  __shared__ float invX[8], invG[8], lscA[8], axv[8];
  __shared__ float pfs;

  const int tid = threadIdx.x;
  const int r0  = blockIdx.x * 8;

  for (int i = tid; i < 1600; i += 256) wih2s[i] = W_ih2[i];
  if (tid < 20) { c10[tid] = c1_0[tid]; c20[tid] = c2_0[tid]; }
  if (tid < 80) {                                // folded gate-1 constants
    float s = b_ih1[tid] + b_hh1[tid];
    for (int j = 0; j < 20; ++j) s += W_hh1[tid*20+j]*h1_0[j];
    c1c[tid] = s;
  } else if (tid < 160) {                        // folded gate-2 constants
    const int k = tid - 80;
    float s = b_ih2[k] + b_hh2[k];
    for (int j = 0; j < 20; ++j) s += W_hh2[k*20+j]*h2_0[j];
    c2c[k] = s;
  } else if (tid < 240) {                        // loss column of W_ih1
    const int k = tid - 160;
    lcol[k] = W_ih1[(size_t)k*4097 + 2048];
  } else if (tid == 240) {                       // poly factor
    const float tv = (float)(*tptr);
    float pf = 0.f, term = 1.f;
    for (int j = 0; j < 3; ++j) {
      float aa = alpha_raw[j];
      float sp = (aa > 20.f) ? aa : log1pf(__expf(aa));
      pf += sp*term; term *= tv;                 // t^0 == 1 even at t=0
    }
    pfs = pf * powf(0.99f, tv);
  }

  // reduce partials: 8 rows x 40 f32x4, NT loads
  for (int idx = tid; idx < 320; idx += 256) {
    const int r = idx / 40, c4 = idx - r*40;
    f32x4 s = (f32x4){0.f,0.f,0.f,0.f};
    #pragma unroll
    for (int sl = 0; sl < NS; ++sl) {
      const f32x4 v = __builtin_nontemporal_load(
          (const f32x4*)(ws + PART + ((size_t)sl*4096 + r0 + r)*160 + c4*4));
      s.x += v.x; s.y += v.y; s.z += v.z; s.w += v.w;
    }
    *(f32x4*)&raw[r][c4*4] = s;
  }
  if (tid < 8) {                                 // norms across slices
    float ax = 0.f, ag = 0.f;
    #pragma unroll
    for (int sl = 0; sl < NS; ++sl) {
      ax = fmaxf(ax, ws[NORM + (size_t)sl*4096 + r0 + tid]);
      ag = fmaxf(ag, ws[NORM + ((size_t)NS + sl)*4096 + r0 + tid]);
    }
    ax = (ax > 0.f) ? ax : 1.0f;  axv[tid] = ax;  invX[tid] = 1.0f/ax;
    ag = (ag > 0.f) ? ag : 1.0f;  invG[tid] = 1.0f/ag;
    float l  = loss[r0 + tid];
    float al = fabsf(l); al = (al > 0.f) ? al : 1.0f;
    lscA[tid] = l / al;
  }
  __syncthreads();

  if (tid < 8) wsw[AXPF + r0 + tid] = pfs * axv[tid];

  for (int q = 0; q < 3; ++q) {                  // gates 1 (8x80)
    const int idx = q*256 + tid;
    if (idx < 640) {
      const int r = idx / 80, k2 = idx - r*80;
      g1[r][k2] = raw[r][k2]*invX[r] + raw[r][80+k2]*invG[r]
                + lcol[k2]*lscA[r] + c1c[k2];
    }
  }
  __syncthreads();

  if (tid < 160) {                               // cell 1
    const int r = tid / 20, j = tid - r*20;
    const float gi = g1[r][j], gf = g1[r][20+j], gc = g1[r][40+j], go = g1[r][60+j];
    const float c1 = fsig(gf)*c10[j] + fsig(gi)*ftanh(gc);
    h1s[r][j] = fsig(go)*ftanh(c1);
  }
  __syncthreads();

  for (int q = 0; q < 3; ++q) {                  // gates 2
    const int idx = q*256 + tid;
    if (idx < 640) {
      const int r = idx / 80, k2 = idx - r*80;
      float s = c2c[k2];
      #pragma unroll
      for (int j = 0; j < 20; ++j) s += wih2s[k2*20+j]*h1s[r][j];
      g1[r][k2] = s;
    }
  }
  __syncthreads();

  if (tid < 160) {                               // cell 2 -> h2 to ws
    const int r = tid / 20, j = tid - r*20;
    const float gi = g1[r][j], gf = g1[r][20+j], gc = g1[r][40+j], go = g1[r][60+j];
    const float c2v = fsig(gf)*c20[j] + fsig(gi)*ftanh(gc);
    wsw[H2S + (size_t)(r0 + r)*20 + j] = fsig(go)*ftanh(c2v);
  }
}

// output GEMM: grid 64 rowblocks x 8 dblocks (per-XCD W_out slice, L2-hot).
// Thread owns one d-column, loops 64 rows from LDS h2. Write-bound.
__global__ __launch_bounds__(256,4) void outgemm_kernel(
    const float* __restrict__ W_out, const float* __restrict__ b_out,
    const float* ws, float* __restrict__ out)
{
  __shared__ float h2s[64][20];
  __shared__ float axs[64];
  const int tid = threadIdx.x;
  const int db = blockIdx.x & 7, rbk = blockIdx.x >> 3;
  const int row0 = rbk * 64;
  const int d = db*256 + tid;

  for (int i = tid; i < 1280; i += 256) (&h2s[0][0])[i] = ws[H2S + (size_t)row0*20 + i];
  if (tid < 64) axs[tid] = ws[AXPF + row0 + tid];
  __syncthreads();

  const float4* wr = (const float4*)(W_out + (size_t)d*20);
  const float4 w0 = wr[0], w1 = wr[1], w2 = wr[2], w3 = wr[3], w4 = wr[4];
  const float bo = b_out[d];

  #pragma unroll 4
  for (int r = 0; r < 64; ++r) {
    const float4* hp = (const float4*)&h2s[r][0];
    const float4 h0 = hp[0], h1v = hp[1], h2v = hp[2], h3v = hp[3], h4v = hp[4];
    float v = bo;
    v += w0.x*h0.x  + w0.y*h0.y  + w0.z*h0.z  + w0.w*h0.w;
    v += w1.x*h1v.x + w1.y*h1v.y + w1.z*h1v.z + w1.w*h1v.w;
    v += w2.x*h2v.x + w2.y*h2v.y + w2.z*h2v.z + w2.w*h2v.w;
    v += w3.x*h3v.x + w3.y*h3v.y + w3.z*h3v.z + w3.w*h3v.w;
    v += w4.x*h4v.x + w4.y*h4v.y + w4.z*h4v.z + w4.w*h4v.w;
    __builtin_nontemporal_store(axs[r] * ftanh(v),
                                &out[(size_t)(row0+r)*2048 + d]);
  }
}

extern "C" void kernel_launch(void* const* d_in, const int* in_sizes, int n_in,
                              void* d_out, int out_size, void* d_ws, size_t ws_size,
                              hipStream_t stream)
{
  const float* x      = (const float*)d_in[0];
  const float* loss   = (const float*)d_in[1];
  const float* grad   = (const float*)d_in[2];
  const float* W_ih1  = (const float*)d_in[3];
  const float* b_ih1  = (const float*)d_in[4];
  const float* W_hh1  = (const float*)d_in[5];
  const float* b_hh1  = (const float*)d_in[6];
  const float* W_ih2  = (const float*)d_in[7];
  const float* b_ih2  = (const float*)d_in[8];
  const float* W_hh2  = (const float*)d_in[9];
  const float* b_hh2  = (const float*)d_in[10];
  const float* W_out  = (const float*)d_in[11];
  const float* b_out  = (const float*)d_in[12];
  const float* h1_0   = (const float*)d_in[13];
  const float* c1_0   = (const float*)d_in[14];
  const float* h2_0   = (const float*)d_in[15];
  const float* c2_0   = (const float*)d_in[16];
  const float* alpha  = (const float*)d_in[17];
  const int*   t      = (const int*)d_in[18];
  float* ws  = (float*)d_ws;
  float* out = (float*)d_out;

  const size_t base = (size_t)PART * sizeof(float);
  const size_t per_slice = (size_t)4096 * 160 * sizeof(float);
  if (ws_size >= base + 16*per_slice) {
    hipLaunchKernelGGL(gemm_kernel<16>, dim3(64*16), dim3(512), 0, stream,
                       x, grad, W_ih1, ws);
    hipLaunchKernelGGL(tail_kernel<16>, dim3(512), dim3(256), 0, stream,
                       loss, W_ih1, b_ih1, W_hh1, b_hh1, W_ih2, b_ih2, W_hh2,
                       b_hh2, h1_0, h2_0, c1_0, c2_0, alpha, t, ws, ws);
  } else if (ws_size >= base + 8*per_slice) {
    hipLaunchKernelGGL(gemm_kernel<8>, dim3(64*8), dim3(512), 0, stream,
                       x, grad, W_ih1, ws);
    hipLaunchKernelGGL(tail_kernel<8>, dim3(512), dim3(256), 0, stream,
                       loss, W_ih1, b_ih1, W_hh1, b_hh1, W_ih2, b_ih2, W_hh2,
                       b_hh2, h1_0, h2_0, c1_0, c2_0, alpha, t, ws, ws);
  } else {
    hipLaunchKernelGGL(gemm_kernel<4>, dim3(64*4), dim3(512), 0, stream,
                       x, grad, W_ih1, ws);
    hipLaunchKernelGGL(tail_kernel<4>, dim3(512), dim3(256), 0, stream,
                       loss, W_ih1, b_ih1, W_hh1, b_hh1, W_ih2, b_ih2, W_hh2,
                       b_hh2, h1_0, h2_0, c1_0, c2_0, alpha, t, ws, ws);
  }
  hipLaunchKernelGGL(outgemm_kernel, dim3(512), dim3(256), 0, stream,
                     W_out, b_out, ws, out);
}

// Round 14
// 53.533 us; speedup vs baseline: 7.1001x; 1.1877x over previous
//
#include <hip/hip_runtime.h>

typedef __attribute__((ext_vector_type(8))) short short8v;
typedef __attribute__((ext_vector_type(4))) float f32x4;
typedef __attribute__((ext_vector_type(4))) unsigned u32x4;

// ws float offsets
#define NORM  0               // [2][16][4096] per-slice row inf-norm maxes (f32)
#define H2S   131072          // [4096][20] h2 state
#define AXPF  212992          // [4096] pf * ax[row]
#define PART  217088          // bf16 partials [NS][4096][160] (ushort), from here

__device__ __forceinline__ float fsig(float x){ return 1.0f/(1.0f + __expf(-x)); }
__device__ __forceinline__ float ftanh(float x){ float e = __expf(2.0f*x); return 1.0f - 2.0f/(e+1.0f); }
__device__ __forceinline__ unsigned short f2bf_rne(float f){
  unsigned u = __float_as_uint(f);
  u += 0x7fffu + ((u >> 16) & 1u);
  return (unsigned short)(u >> 16);
}
__device__ __forceinline__ unsigned pack2bf(float lo, float hi){
  unsigned a = __float_as_uint(lo) + 0x8000u;
  unsigned b = __float_as_uint(hi) + 0x8000u;
  return (a >> 16) | (b & 0xFFFF0000u);
}

// GEMM: grid = 64 rowblocks x NS kslices, 512 thr = 8 waves (4 m-tiles x 2 parts).
// KS = 2048/NS per part; 128-col chunks staged from W_ih1 (f32->bf16, swizzled
// 40KB LDS). A fragments issued upfront per chunk; next chunk's A prefetched
// during compute. Partials stored bf16 (halves RT traffic); norms exclusive f32.
template<int NS>
__global__ __launch_bounds__(512,2) void gemm_kernel(
    const float* __restrict__ x, const float* __restrict__ grad,
    const float* __restrict__ W_ih1, float* __restrict__ ws)
{
  constexpr int KS  = 2048 / NS;
  constexpr int NCH = KS / 128;
  __shared__ unsigned short bs[160*128];   // 40 KB

  const int tid = threadIdx.x;
  const int w = tid >> 6, lane = tid & 63;
  const int mt = w >> 1, gh = w & 1;       // m-tile 0..3, part 0=x 1=grad
  const int m = lane & 15, kg = lane >> 4;
  const int rb = blockIdx.x / NS, ksl = blockIdx.x % NS;
  const int r0 = rb*64;
  const int kb0 = ksl*KS;

  const float* Ap = (gh ? grad : x) + (size_t)(r0 + mt*16 + m)*2048 + kg*8;
  const int xk = (m & 7) << 4;
  // stage mapping: lane-group of 64 = one gate row, 64 f32-pairs = 512B coalesced
  const int sg = tid >> 6;                 // base gate stride per q: 8 gates
  const int sp = tid & 63;                 // pair index within 128-col chunk

  f32x4 acc[5];
  #pragma unroll
  for (int t = 0; t < 5; ++t) acc[t] = (f32x4){0.f,0.f,0.f,0.f};
  float vm = 0.f;

  // A for chunk 0 upfront
  f32x4 a[4][2];
  #pragma unroll
  for (int ks = 0; ks < 4; ++ks) {
    a[ks][0] = __builtin_nontemporal_load((const f32x4*)(Ap + kb0 + ks*32));
    a[ks][1] = __builtin_nontemporal_load((const f32x4*)(Ap + kb0 + ks*32 + 4));
  }

  #pragma unroll
  for (int c = 0; c < NCH; ++c) {
    const int kb = kb0 + c*128;
    // ---- stage chunk: 160 gates x 64 pairs, f32 -> bf16, swizzled ----
    #pragma unroll
    for (int q = 0; q < 20; ++q) {
      const int g = q*8 + sg;
      const float* src = W_ih1 + (size_t)((g < 80) ? g : g - 80)*4097
                       + ((g < 80) ? 0 : 2049) + kb + 2*sp;
      const unsigned pk = pack2bf(src[0], src[1]);
      *(unsigned*)((char*)bs + g*256
                   + (((sp >> 2)*16) ^ ((g & 7) << 4)) + (sp & 3)*4) = pk;
    }
    __syncthreads();
    // prefetch next chunk's A
    f32x4 an[4][2];
    if (c + 1 < NCH) {
      #pragma unroll
      for (int ks = 0; ks < 4; ++ks) {
        an[ks][0] = __builtin_nontemporal_load((const f32x4*)(Ap + kb + 128 + ks*32));
        an[ks][1] = __builtin_nontemporal_load((const f32x4*)(Ap + kb + 128 + ks*32 + 4));
      }
    }
    // ---- 4 k-steps x 5 MFMA ----
    #pragma unroll
    for (int ks = 0; ks < 4; ++ks) {
      const f32x4 a0 = a[ks][0], a1 = a[ks][1];
      vm = fmaxf(vm, fmaxf(fmaxf(fabsf(a0.x),fabsf(a0.y)), fmaxf(fabsf(a0.z),fabsf(a0.w))));
      vm = fmaxf(vm, fmaxf(fmaxf(fabsf(a1.x),fabsf(a1.y)), fmaxf(fabsf(a1.z),fabsf(a1.w))));
      union { unsigned u[4]; short8v v; } A_;
      A_.u[0] = pack2bf(a0.x, a0.y);
      A_.u[1] = pack2bf(a0.z, a0.w);
      A_.u[2] = pack2bf(a1.x, a1.y);
      A_.u[3] = pack2bf(a1.z, a1.w);
      const short8v af = A_.v;
      const int kof = (ks*64 + kg*16) ^ xk;
      #pragma unroll
      for (int t = 0; t < 5; ++t) {
        const int lg = gh*80 + t*16 + m;
        const short8v bf = *(const short8v*)((char*)bs + lg*256 + kof);
        acc[t] = __builtin_amdgcn_mfma_f32_16x16x32_bf16(af, bf, acc[t], 0, 0, 0);
      }
    }
    if (c + 1 < NCH) {
      __syncthreads();                 // bs reads done before restage
      #pragma unroll
      for (int ks = 0; ks < 4; ++ks) { a[ks][0] = an[ks][0]; a[ks][1] = an[ks][1]; }
    }
  }

  // ---- per-slice row inf-norm: reduce kg lanes, exclusive f32 store ----
  vm = fmaxf(vm, __shfl_xor(vm, 16));
  vm = fmaxf(vm, __shfl_xor(vm, 32));
  if (lane < 16)
    ws[NORM + ((size_t)gh*NS + ksl)*4096 + r0 + mt*16 + m] = vm;

  // ---- partials: bf16, [slice][row][gate], exclusive ownership ----
  unsigned short* pp = (unsigned short*)(ws + PART)
                     + ((size_t)ksl*4096 + r0 + mt*16 + kg*4)*160 + gh*80 + m;
  #pragma unroll
  for (int t = 0; t < 5; ++t)
    #pragma unroll
    for (int r = 0; r < 4; ++r)
      pp[(size_t)r*160 + t*16] = f2bf_rne(acc[t][r]);
}

// tail: 512 blocks x 256 thr; 8 rows. Folded constants computed locally,
// bf16 partial reduce + norm reduce, gates -> cells -> h2 + pf*ax to ws.
template<int NS>
__global__ __launch_bounds__(256,4) void tail_kernel(
    const float* __restrict__ loss, const float* __restrict__ W_ih1,
    const float* __restrict__ b_ih1, const float* __restrict__ W_hh1,
    const float* __restrict__ b_hh1, const float* __restrict__ W_ih2,
    const float* __restrict__ b_ih2, const float* __restrict__ W_hh2,
    const float* __restrict__ b_hh2, const float* __restrict__ h1_0,
    const float* __restrict__ h2_0, const float* __restrict__ c1_0,
    const float* __restrict__ c2_0, const float* __restrict__ alpha_raw,
    const int* __restrict__ tptr, const float* ws, float* __restrict__ wsw)
{
  __shared__ float raw[8][160];
  __shared__ float g1[8][80];
  __shared__ float wih2s[1600];
  __shared__ float h1s[8][20];
  __shared__ float c1c[80], c2c[80], lcol[80];
  __shared__ float c10[20], c20[20];
  __shared__ float invX[8], invG[8], lscA[8], axv[8];
  __shared__ float pfs;

  const int tid = threadIdx.x;
  const int r0  = blockIdx.x * 8;

  for (int i = tid; i < 1600; i += 256) wih2s[i] = W_ih2[i];
  if (tid < 20) { c10[tid] = c1_0[tid]; c20[tid] = c2_0[tid]; }
  if (tid < 80) {                                // folded gate-1 constants
    float s = b_ih1[tid] + b_hh1[tid];
    for (int j = 0; j < 20; ++j) s += W_hh1[tid*20+j]*h1_0[j];
    c1c[tid] = s;
  } else if (tid < 160) {                        // folded gate-2 constants
    const int k = tid - 80;
    float s = b_ih2[k] + b_hh2[k];
    for (int j = 0; j < 20; ++j) s += W_hh2[k*20+j]*h2_0[j];
    c2c[k] = s;
  } else if (tid < 240) {                        // loss column of W_ih1
    const int k = tid - 160;
    lcol[k] = W_ih1[(size_t)k*4097 + 2048];
  } else if (tid == 240) {                       // poly factor
    const float tv = (float)(*tptr);
    float pf = 0.f, term = 1.f;
    for (int j = 0; j < 3; ++j) {
      float aa = alpha_raw[j];
      float sp = (aa > 20.f) ? aa : log1pf(__expf(aa));
      pf += sp*term; term *= tv;                 // t^0 == 1 even at t=0
    }
    pfs = pf * powf(0.99f, tv);
  }

  // reduce bf16 partials: 8 rows x 20 groups of 8 gates
  const unsigned short* pbase = (const unsigned short*)(ws + PART);
  if (tid < 160) {
    const int r = tid / 20, c8 = tid - (tid/20)*20;
    float s[8];
    #pragma unroll
    for (int j = 0; j < 8; ++j) s[j] = 0.f;
    #pragma unroll
    for (int sl = 0; sl < NS; ++sl) {
      const u32x4 v = __builtin_nontemporal_load(
          (const u32x4*)(pbase + ((size_t)sl*4096 + r0 + r)*160 + c8*8));
      #pragma unroll
      for (int j = 0; j < 4; ++j) {
        s[2*j]   += __uint_as_float(v[j] << 16);
        s[2*j+1] += __uint_as_float(v[j] & 0xFFFF0000u);
      }
    }
    #pragma unroll
    for (int j = 0; j < 8; ++j) raw[r][c8*8+j] = s[j];
  }
  if (tid < 8) {                                 // norms across slices
    float ax = 0.f, ag = 0.f;
    #pragma unroll
    for (int sl = 0; sl < NS; ++sl) {
      ax = fmaxf(ax, ws[NORM + (size_t)sl*4096 + r0 + tid]);
      ag = fmaxf(ag, ws[NORM + ((size_t)NS + sl)*4096 + r0 + tid]);
    }
    ax = (ax > 0.f) ? ax : 1.0f;  axv[tid] = ax;  invX[tid] = 1.0f/ax;
    ag = (ag > 0.f) ? ag : 1.0f;  invG[tid] = 1.0f/ag;
    float l  = loss[r0 + tid];
    float al = fabsf(l); al = (al > 0.f) ? al : 1.0f;
    lscA[tid] = l / al;
  }
  __syncthreads();

  if (tid < 8) wsw[AXPF + r0 + tid] = pfs * axv[tid];

  for (int q = 0; q < 3; ++q) {                  // gates 1 (8x80)
    const int idx = q*256 + tid;
    if (idx < 640) {
      const int r = idx / 80, k2 = idx - r*80;
      g1[r][k2] = raw[r][k2]*invX[r] + raw[r][80+k2]*invG[r]
                + lcol[k2]*lscA[r] + c1c[k2];
    }
  }
  __syncthreads();

  if (tid < 160) {                               // cell 1
    const int r = tid / 20, j = tid - r*20;
    const float gi = g1[r][j], gf = g1[r][20+j], gc = g1[r][40+j], go = g1[r][60+j];
    const float c1 = fsig(gf)*c10[j] + fsig(gi)*ftanh(gc);
    h1s[r][j] = fsig(go)*ftanh(c1);
  }
  __syncthreads();

  for (int q = 0; q < 3; ++q) {                  // gates 2
    const int idx = q*256 + tid;
    if (idx < 640) {
      const int r = idx / 80, k2 = idx - r*80;
      float s = c2c[k2];
      #pragma unroll
      for (int j = 0; j < 20; ++j) s += wih2s[k2*20+j]*h1s[r][j];
      g1[r][k2] = s;
    }
  }
  __syncthreads();

  if (tid < 160) {                               // cell 2 -> h2 to ws
    const int r = tid / 20, j = tid - r*20;
    const float gi = g1[r][j], gf = g1[r][20+j], gc = g1[r][40+j], go = g1[r][60+j];
    const float c2v = fsig(gf)*c20[j] + fsig(gi)*ftanh(gc);
    wsw[H2S + (size_t)(r0 + r)*20 + j] = fsig(go)*ftanh(c2v);
  }
}

// output GEMM: grid 64 rowblocks x 8 dblocks (per-XCD W_out slice, L2-hot).
__global__ __launch_bounds__(256,4) void outgemm_kernel(
    const float* __restrict__ W_out, const float* __restrict__ b_out,
    const float* ws, float* __restrict__ out)
{
  __shared__ float h2s[64][20];
  __shared__ float axs[64];
  const int tid = threadIdx.x;
  const int db = blockIdx.x & 7, rbk = blockIdx.x >> 3;
  const int row0 = rbk * 64;
  const int d = db*256 + tid;

  for (int i = tid; i < 1280; i += 256) (&h2s[0][0])[i] = ws[H2S + (size_t)row0*20 + i];
  if (tid < 64) axs[tid] = ws[AXPF + row0 + tid];
  __syncthreads();

  const float4* wr = (const float4*)(W_out + (size_t)d*20);
  const float4 w0 = wr[0], w1 = wr[1], w2 = wr[2], w3 = wr[3], w4 = wr[4];
  const float bo = b_out[d];

  #pragma unroll 4
  for (int r = 0; r < 64; ++r) {
    const float4* hp = (const float4*)&h2s[r][0];
    const float4 h0 = hp[0], h1v = hp[1], h2v = hp[2], h3v = hp[3], h4v = hp[4];
    float v = bo;
    v += w0.x*h0.x  + w0.y*h0.y  + w0.z*h0.z  + w0.w*h0.w;
    v += w1.x*h1v.x + w1.y*h1v.y + w1.z*h1v.z + w1.w*h1v.w;
    v += w2.x*h2v.x + w2.y*h2v.y + w2.z*h2v.z + w2.w*h2v.w;
    v += w3.x*h3v.x + w3.y*h3v.y + w3.z*h3v.z + w3.w*h3v.w;
    v += w4.x*h4v.x + w4.y*h4v.y + w4.z*h4v.z + w4.w*h4v.w;
    __builtin_nontemporal_store(axs[r] * ftanh(v),
                                &out[(size_t)(row0+r)*2048 + d]);
  }
}

extern "C" void kernel_launch(void* const* d_in, const int* in_sizes, int n_in,
                              void* d_out, int out_size, void* d_ws, size_t ws_size,
                              hipStream_t stream)
{
  const float* x      = (const float*)d_in[0];
  const float* loss   = (const float*)d_in[1];
  const float* grad   = (const float*)d_in[2];
  const float* W_ih1  = (const float*)d_in[3];
  const float* b_ih1  = (const float*)d_in[4];
  const float* W_hh1  = (const float*)d_in[5];
  const float* b_hh1  = (const float*)d_in[6];
  const float* W_ih2  = (const float*)d_in[7];
  const float* b_ih2  = (const float*)d_in[8];
  const float* W_hh2  = (const float*)d_in[9];
  const float* b_hh2  = (const float*)d_in[10];
  const float* W_out  = (const float*)d_in[11];
  const float* b_out  = (const float*)d_in[12];
  const float* h1_0   = (const float*)d_in[13];
  const float* c1_0   = (const float*)d_in[14];
  const float* h2_0   = (const float*)d_in[15];
  const float* c2_0   = (const float*)d_in[16];
  const float* alpha  = (const float*)d_in[17];
  const int*   t      = (const int*)d_in[18];
  float* ws  = (float*)d_ws;
  float* out = (float*)d_out;

  const size_t base = (size_t)PART * sizeof(float);
  const size_t per_slice = (size_t)4096 * 160 * sizeof(unsigned short);
  if (ws_size >= base + 8*per_slice) {
    hipLaunchKernelGGL(gemm_kernel<8>, dim3(64*8), dim3(512), 0, stream,
                       x, grad, W_ih1, ws);
    hipLaunchKernelGGL(tail_kernel<8>, dim3(512), dim3(256), 0, stream,
                       loss, W_ih1, b_ih1, W_hh1, b_hh1, W_ih2, b_ih2, W_hh2,
                       b_hh2, h1_0, h2_0, c1_0, c2_0, alpha, t, ws, ws);
  } else {
    hipLaunchKernelGGL(gemm_kernel<4>, dim3(64*4), dim3(512), 0, stream,
                       x, grad, W_ih1, ws);
    hipLaunchKernelGGL(tail_kernel<4>, dim3(512), dim3(256), 0, stream,
                       loss, W_ih1, b_ih1, W_hh1, b_hh1, W_ih2, b_ih2, W_hh2,
                       b_hh2, h1_0, h2_0, c1_0, c2_0, alpha, t, ws, ws);
  }
  hipLaunchKernelGGL(outgemm_kernel, dim3(512), dim3(256), 0, stream,
                     W_out, b_out, ws, out);
}